// Round 12
// baseline (166.456 us; speedup 1.0000x reference)
//
#include <hip/hip_runtime.h>

#define CUTOFF 5.0f
#define CUTOFF2 25.0f
#define GAMMA 40.96f              // (32/5)^2
#define MU_STEP 0.16129032f       // 5/31
#define INV_MU 6.2f               // 31/5
#define PI_F 3.14159265358979f
#define MAXDEG 64                 // Poisson(4.42): P(deg>=25) ~ 1e-12

// ---------------------------------------------------------------------------
// R12: R9's 3-dispatch structure; gather re-parallelized as 32 threads/node
// (2 edge-slots x 16 channels, 8 nodes/block) with the R8-proven 2-edge
// unroll body -> VGPR stays ~64 (R11 showed 4-edge unroll costs occupancy:
// VGPR 92, occ 18.5%, regression). Slots fold via one shfl_xor(16).
// LDS/block ~12.5 KB -> 8 blocks/CU; trips/thread ~1.2 vs 2.2.
// ---------------------------------------------------------------------------

__global__ __launch_bounds__(256) void k_fill_direct(
    const float* __restrict__ pos, const int* __restrict__ ei,
    int* __restrict__ deg, int* __restrict__ rec, int E)
{
    int e = blockIdx.x * 256 + threadIdx.x;
    if (e >= E) return;
    int src = ei[e], dst = ei[E + e];
    float dx = pos[dst*3+0] - pos[src*3+0];
    float dy = pos[dst*3+1] - pos[src*3+1];
    float dz = pos[dst*3+2] - pos[src*3+2];
    float d2 = dx*dx + dy*dy + dz*dz;
    if (d2 < CUTOFF2) {                       // == (sqrt(d2+1e-12) < 5), monotone
        int slot = atomicAdd(&deg[dst], 1);
        if (slot < MAXDEG) rec[dst*MAXDEG + slot] = src;
    }
}

// Gather + finalize: 8 nodes/block; thread = (node nl, slot s, channel c).
// Slot s walks edges {4k+2s, 4k+2s+1}; 16-lane channel group cooperatively
// computes the pair's RBF exps (lanes 0-7 edge0, 8-15 edge1).
__global__ __launch_bounds__(256) void k_gather_finalize(
    const float* __restrict__ h, const float* __restrict__ pos,
    const int* __restrict__ rec, const int* __restrict__ deg,
    const float* __restrict__ Wrbf, const float* __restrict__ Wout,
    const float* __restrict__ Wsgp, float* __restrict__ out, int N)
{
    __shared__ float s_wr[512];        // W_rbf [32,16]
    __shared__ float s_Wout[256];
    __shared__ float s_Wsgp[256];
    __shared__ float s_agg[8*132];     // stride 132 breaks power-of-2 conflicts
    __shared__ float s_h[8*132];

    const int t  = threadIdx.x;
    const int nl = t >> 5;             // node 0..7
    const int s  = (t >> 4) & 1;       // edge slot 0..1
    const int c  = t & 15;             // channel
    const int lane  = t & 63;
    const int gbase = lane & 48;       // 16-lane channel-group base within wave
    const long long nodeBase = (long long)blockIdx.x * 8;
    const long long n = nodeBase + nl;

    s_wr[t]       = Wrbf[t];
    s_wr[t + 256] = Wrbf[t + 256];
    s_Wout[t] = Wout[t];
    s_Wsgp[t] = Wsgp[t];

    // stage h rows: 8 nodes x 32 float4 = 256 float4, one per thread
    {
        int nn = t >> 5, r = t & 31;
        long long node = nodeBase + nn;
        float4 vh = make_float4(0,0,0,0);
        if (node < N) vh = *(const float4*)(h + node*128 + (long long)r*4);
        *(float4*)(&s_h[nn*132 + r*4]) = vh;
    }
    __syncthreads();

    float m0=0,m1=0,m2=0,m3=0,m4=0,m5=0,m6=0,m7=0;
    if (n < N) {
        const float px = pos[n*3+0], py = pos[n*3+1], pz = pos[n*3+2];
        const int start = (int)n * MAXDEG;
        const int dg    = min(deg[n], MAXDEG);
        for (int base = 2*s; base < dg; base += 4) {
            const int i1ok = (base + 1 < dg) ? 1 : 0;
            const int s0 = rec[start + base];
            const int s1 = rec[start + base + i1ok];   // repeats s0 on odd tail

            // 2 independent 32B h chains in flight during the math
            const float4* hp0 = (const float4*)(h + (((long long)s0*16 + c) << 3));
            const float4* hp1 = (const float4*)(h + (((long long)s1*16 + c) << 3));
            const float4 A0 = hp0[0], B0 = hp0[1];
            const float4 A1 = hp1[0], B1 = hp1[1];

            const float dx0 = px - pos[s0*3+0];
            const float dy0 = py - pos[s0*3+1];
            const float dz0 = pz - pos[s0*3+2];
            const float dx1 = px - pos[s1*3+0];
            const float dy1 = py - pos[s1*3+1];
            const float dz1 = pz - pos[s1*3+2];

            const float d0 = sqrtf(dx0*dx0 + dy0*dy0 + dz0*dz0 + 1e-12f);
            const float d1 = sqrtf(dx1*dx1 + dy1*dy1 + dz1*dz1 + 1e-12f);
            const float inv0 = 1.0f / d0, inv1 = 1.0f / d1;
            const float ux0 = dx0*inv0, uy0 = dy0*inv0, uz0 = dz0*inv0;
            const float ux1 = dx1*inv1, uy1 = dy1*inv1, uz1 = dz1*inv1;
            const float env0 = 0.5f * (__cosf(PI_F * d0 * (1.0f/CUTOFF)) + 1.0f);
            const float env1 = 0.5f * (__cosf(PI_F * d1 * (1.0f/CUTOFF)) + 1.0f);

            // 7-term RBF window clamped into [0,31] (dropped terms < 4e-8)
            const int kl0 = min(max(0, __float2int_rn(d0 * INV_MU) - 3), 25);
            const int kl1 = min(max(0, __float2int_rn(d1 * INV_MU) - 3), 25);

            // cooperative exp: lanes 0-7 of the group cover edge0's window,
            // lanes 8-15 cover edge1's.
            const int   sel   = c >> 3;
            const float dsel  = sel ? d1 : d0;
            const int   klsel = sel ? kl1 : kl0;
            const float xx = dsel - MU_STEP * (float)(klsel + (c & 7));
            const float ee = __expf(-GAMMA * xx * xx);

            float w0 = 0.0f, w1 = 0.0f;
            #pragma unroll
            for (int j = 0; j < 7; ++j) {
                const float e0 = __shfl(ee, gbase + j);
                const float e1 = __shfl(ee, gbase + 8 + j);
                w0 += e0 * s_wr[(kl0 + j)*16 + c];
                w1 += e1 * s_wr[(kl1 + j)*16 + c];
            }
            w0 *= env0;
            w1 *= env1 * (float)i1ok;

            // gp(a,u), u grade-1; blades: 0:1 1:e1 2:e2 3:e3 4:e12 5:e13 6:e23 7:e123
            m0 += (A0.y*ux0 + A0.z*uy0 + A0.w*uz0) * w0 + (A1.y*ux1 + A1.z*uy1 + A1.w*uz1) * w1;
            m1 += (A0.x*ux0 + B0.x*uy0 + B0.y*uz0) * w0 + (A1.x*ux1 + B1.x*uy1 + B1.y*uz1) * w1;
            m2 += (A0.x*uy0 - B0.x*ux0 + B0.z*uz0) * w0 + (A1.x*uy1 - B1.x*ux1 + B1.z*uz1) * w1;
            m3 += (A0.x*uz0 - B0.y*ux0 - B0.z*uy0) * w0 + (A1.x*uz1 - B1.y*ux1 - B1.z*uy1) * w1;
            m4 += (A0.y*uy0 - A0.z*ux0 + B0.w*uz0) * w0 + (A1.y*uy1 - A1.z*ux1 + B1.w*uz1) * w1;
            m5 += (A0.y*uz0 - A0.w*ux0 - B0.w*uy0) * w0 + (A1.y*uz1 - A1.w*ux1 - B1.w*uy1) * w1;
            m6 += (A0.z*uz0 - A0.w*uy0 + B0.w*ux0) * w0 + (A1.z*uz1 - A1.w*uy1 + B1.w*ux1) * w1;
            m7 += (B0.z*ux0 - B0.y*uy0 + B0.x*uz0) * w0 + (B1.z*ux1 - B1.y*uy1 + B1.x*uz1) * w1;
        }
    }

    // fold the two edge slots (lane bit 4)
    m0 += __shfl_xor(m0, 16); m1 += __shfl_xor(m1, 16);
    m2 += __shfl_xor(m2, 16); m3 += __shfl_xor(m3, 16);
    m4 += __shfl_xor(m4, 16); m5 += __shfl_xor(m5, 16);
    m6 += __shfl_xor(m6, 16); m7 += __shfl_xor(m7, 16);

    if (s == 0) {
        float* ag = &s_agg[nl*132 + c*8];
        *(float4*)(ag)     = make_float4(m0, m1, m2, m3);
        *(float4*)(ag + 4) = make_float4(m4, m5, m6, m7);
    }
    __syncthreads();

    if (t < 128) {
        const int n2 = t >> 4;
        const int o  = t & 15;
        const float* A = &s_agg[n2*132];
        const float* H = &s_h[n2*132];

        float o0=0,o1=0,o2=0,o3=0,o4=0,o5=0,o6=0,o7=0;
        float q0=0,q1=0,q2=0,q3=0,q4=0,q5=0,q6=0,q7=0;
        #pragma unroll
        for (int cc = 0; cc < 16; ++cc) {
            const float wo = s_Wout[cc*16 + o];
            const float ws = s_Wsgp[cc*16 + o];
            const float* a  = A + cc*8;
            const float* hh = H + cc*8;
            o0 += a[0]*wo; o1 += a[1]*wo; o2 += a[2]*wo; o3 += a[3]*wo;
            o4 += a[4]*wo; o5 += a[5]*wo; o6 += a[6]*wo; o7 += a[7]*wo;
            q0 += hh[0]*ws; q1 += hh[1]*ws; q2 += hh[2]*ws; q3 += hh[3]*ws;
            q4 += hh[4]*ws; q5 += hh[5]*ws; q6 += hh[6]*ws; q7 += hh[7]*ws;
        }

        // res = out + gp(out, q), full Cl(3,0) Cayley product
        const float r0 = o0 + (o0*q0 + o1*q1 + o2*q2 + o3*q3 - o4*q4 - o5*q5 - o6*q6 - o7*q7);
        const float r1 = o1 + (o0*q1 + o1*q0 - o2*q4 - o3*q5 + o4*q2 + o5*q3 - o6*q7 - o7*q6);
        const float r2 = o2 + (o0*q2 + o1*q4 + o2*q0 - o3*q6 - o4*q1 + o5*q7 + o6*q3 + o7*q5);
        const float r3 = o3 + (o0*q3 + o1*q5 + o2*q6 + o3*q0 - o4*q7 - o5*q1 - o6*q2 - o7*q4);
        const float r4 = o4 + (o0*q4 + o1*q2 - o2*q1 + o3*q7 + o4*q0 - o5*q6 + o6*q5 + o7*q3);
        const float r5 = o5 + (o0*q5 + o1*q3 - o2*q7 - o3*q1 + o4*q6 + o5*q0 - o6*q4 - o7*q2);
        const float r6 = o6 + (o0*q6 + o1*q7 + o2*q3 - o3*q2 - o4*q5 + o5*q4 + o6*q0 + o7*q1);
        const float r7 = o7 + (o0*q7 + o1*q6 - o2*q5 + o3*q4 + o4*q3 - o5*q2 + o6*q1 + o7*q0);

        const long long nn = nodeBase + n2;
        if (nn < N) {
            float* op = out + (nn*16 + o)*8;
            *(float4*)(op)     = make_float4(r0, r1, r2, r3);
            *(float4*)(op + 4) = make_float4(r4, r5, r6, r7);
        }
    }
}

extern "C" void kernel_launch(void* const* d_in, const int* in_sizes, int n_in,
                              void* d_out, int out_size, void* d_ws, size_t ws_size,
                              hipStream_t stream) {
    const float* h    = (const float*)d_in[0];   // [N,16,8]
    const float* pos  = (const float*)d_in[1];   // [N,3]
    const int*   ei   = (const int*)d_in[2];     // [2,E]
    const float* Wrbf = (const float*)d_in[3];   // [32,16]
    const float* Wout = (const float*)d_in[4];   // [16,16]
    const float* Wsgp = (const float*)d_in[5];   // [16,16]
    float* out = (float*)d_out;

    const int N = in_sizes[0] / 128;
    const int E = in_sizes[2] / 2;

    // ws layout (ints): deg[N] | rec[N*MAXDEG]  (~13 MB)
    int* deg = (int*)d_ws;
    int* rec = deg + N;

    hipMemsetAsync(deg, 0, (size_t)N * sizeof(int), stream);

    const int eBlocks = (E + 255) / 256;
    k_fill_direct<<<eBlocks, 256, 0, stream>>>(pos, ei, deg, rec, E);

    const int gBlocks = (N + 7) / 8;
    k_gather_finalize<<<gBlocks, 256, 0, stream>>>(
        h, pos, rec, deg, Wrbf, Wout, Wsgp, out, N);
}